// Round 2
// baseline (355.180 us; speedup 1.0000x reference)
//
#include <hip/hip_runtime.h>
#include <hip/hip_bf16.h>

#define NDIM 512
#define NREL 64
#define NCOL 128          // 2 * NREL projection columns
#define KSTEPS (NDIM / 32)

typedef float f32x4 __attribute__((ext_vector_type(4)));
typedef short s16x8 __attribute__((ext_vector_type(8)));

static __device__ __forceinline__ short f2bf_rne(float f) {
    union { float f; unsigned u; } v; v.f = f;
    unsigned u = v.u + 0x7fffu + ((v.u >> 16) & 1u);
    return (short)(u >> 16);
}
static __device__ __forceinline__ float bf2f(short h) {
    union { unsigned u; float f; } v;
    v.u = ((unsigned)(unsigned short)h) << 16;
    return v.f;
}

// ---------- Kernel A: W [64,1024] fp32 -> fragment-major bf16 hi/lo ----------
// B[k][n] = W[n&63][(n>>6)*512 + k];  frag (ks,c): lane l elem i ->
//   k = ks*32 + (l>>4)*8 + i, n = c*16 + (l&15); linear short idx = t.
__global__ __launch_bounds__(256) void prep_B_kernel(
    const float* __restrict__ W, short* __restrict__ Bh, short* __restrict__ Bl)
{
    const int t = blockIdx.x * 256 + threadIdx.x;     // [0, 65536)
    const int i  = t & 7;
    const int l  = (t >> 3) & 63;
    const int c  = (t >> 9) & 7;
    const int ks = t >> 12;
    const int k = ks * 32 + ((l >> 4) << 3) + i;
    const int n = (c << 4) + (l & 15);
    const float w = W[(n & 63) * (2 * NDIM) + (n >> 6) * NDIM + k];
    const short hi = f2bf_rne(w);
    const short lo = f2bf_rne(w - bf2f(hi));
    Bh[t] = hi;
    Bl[t] = lo;
}

// ---------- Kernel B: P[M,128] = emb[M,512] @ B[512,128], bf16 hi/lo split ----------
// Block = 256 threads = 4 waves; wave owns 32 rows (2 x 16-row fragments).
__global__ __launch_bounds__(256) void gemm_proj_kernel(
    const float* __restrict__ emb, const short* __restrict__ Bh,
    const short* __restrict__ Bl, float* __restrict__ P, int M)
{
    const int lane = threadIdx.x & 63;
    const int wave = threadIdx.x >> 6;
    const int rbase = blockIdx.x * 128 + wave * 32;
    const int rcol = lane & 15;
    const int koff = (lane >> 4) << 3;        // 0,8,16,24

    const long r0c = (long)min(rbase + rcol, M - 1) * NDIM;
    const long r1c = (long)min(rbase + 16 + rcol, M - 1) * NDIM;

    f32x4 acc[2][8];
#pragma unroll
    for (int f = 0; f < 2; ++f)
#pragma unroll
        for (int c = 0; c < 8; ++c)
            acc[f][c] = (f32x4){0.f, 0.f, 0.f, 0.f};

    for (int ks = 0; ks < KSTEPS; ++ks) {
        const float* a0p = emb + r0c + ks * 32 + koff;
        const float* a1p = emb + r1c + ks * 32 + koff;
        f32x4 a0a = *(const f32x4*)(a0p);
        f32x4 a0b = *(const f32x4*)(a0p + 4);
        f32x4 a1a = *(const f32x4*)(a1p);
        f32x4 a1b = *(const f32x4*)(a1p + 4);

        s16x8 a0h, a0l, a1h, a1l;
#pragma unroll
        for (int j = 0; j < 4; ++j) {
            short h;
            h = f2bf_rne(a0a[j]); a0h[j]     = h; a0l[j]     = f2bf_rne(a0a[j] - bf2f(h));
            h = f2bf_rne(a0b[j]); a0h[4 + j] = h; a0l[4 + j] = f2bf_rne(a0b[j] - bf2f(h));
            h = f2bf_rne(a1a[j]); a1h[j]     = h; a1l[j]     = f2bf_rne(a1a[j] - bf2f(h));
            h = f2bf_rne(a1b[j]); a1h[4 + j] = h; a1l[4 + j] = f2bf_rne(a1b[j] - bf2f(h));
        }

        const s16x8* bhp = (const s16x8*)(Bh) + (long)ks * 512 + lane;  // s16x8 units
        const s16x8* blp = (const s16x8*)(Bl) + (long)ks * 512 + lane;
#pragma unroll
        for (int c = 0; c < 8; ++c) {
            s16x8 bh = bhp[c * 64];
            s16x8 bl = blp[c * 64];
            acc[0][c] = __builtin_amdgcn_mfma_f32_16x16x32_bf16(a0h, bh, acc[0][c], 0, 0, 0);
            acc[0][c] = __builtin_amdgcn_mfma_f32_16x16x32_bf16(a0l, bh, acc[0][c], 0, 0, 0);
            acc[0][c] = __builtin_amdgcn_mfma_f32_16x16x32_bf16(a0h, bl, acc[0][c], 0, 0, 0);
            acc[1][c] = __builtin_amdgcn_mfma_f32_16x16x32_bf16(a1h, bh, acc[1][c], 0, 0, 0);
            acc[1][c] = __builtin_amdgcn_mfma_f32_16x16x32_bf16(a1l, bh, acc[1][c], 0, 0, 0);
            acc[1][c] = __builtin_amdgcn_mfma_f32_16x16x32_bf16(a1h, bl, acc[1][c], 0, 0, 0);
        }
    }

    // C/D layout: col = lane&15, row = (lane>>4)*4 + reg
#pragma unroll
    for (int f = 0; f < 2; ++f) {
        const int rb = rbase + f * 16 + ((lane >> 4) << 2);
#pragma unroll
        for (int c = 0; c < 8; ++c) {
#pragma unroll
            for (int i = 0; i < 4; ++i) {
                const int r = rb + i;
                if (r < M)
                    P[(long)r * NCOL + c * 16 + rcol] = acc[f][c][i];
            }
        }
    }
}

// ---------- Kernel C: per-triple scalar gather from P ----------
__global__ __launch_bounds__(256) void gather_score_kernel(
    const float* __restrict__ P, const float* __restrict__ b,
    const int* __restrict__ triples, float* __restrict__ out, int T)
{
    const int t = blockIdx.x * 256 + threadIdx.x;
    if (t >= T) return;
    const int s = triples[t];
    const int r = triples[T + t];
    const int o = triples[2 * T + t];
    out[t] = P[(long)s * NCOL + r] + P[(long)o * NCOL + NREL + r] + b[r];
}

// ---------- Fallback: direct gather kernel (round-1, verified) ----------
__global__ __launch_bounds__(256) void kg_score_kernel(
    const float* __restrict__ emb, const float* __restrict__ W,
    const float* __restrict__ b, const int* __restrict__ triples,
    float* __restrict__ out, int T)
{
    const int wid  = (int)((blockIdx.x * (unsigned)blockDim.x + threadIdx.x) >> 6);
    const int lane = threadIdx.x & 63;
    if (wid >= T) return;

    const int s = triples[wid];
    const int r = triples[T + wid];
    const int o = triples[2 * T + wid];

    const float4* __restrict__ srow  = (const float4*)(emb + (long)s * NDIM);
    const float4* __restrict__ orow  = (const float4*)(emb + (long)o * NDIM);
    const float4* __restrict__ wsrow = (const float4*)(W + (long)r * (2 * NDIM));
    const float4* __restrict__ worow = wsrow + NDIM / 4;

    float acc = 0.0f;
#pragma unroll
    for (int k = 0; k < 2; ++k) {
        const int idx = lane + k * 64;
        float4 sv = srow[idx];
        float4 wv = wsrow[idx];
        acc = fmaf(sv.x, wv.x, acc); acc = fmaf(sv.y, wv.y, acc);
        acc = fmaf(sv.z, wv.z, acc); acc = fmaf(sv.w, wv.w, acc);
        float4 ov = orow[idx];
        float4 uv = worow[idx];
        acc = fmaf(ov.x, uv.x, acc); acc = fmaf(ov.y, uv.y, acc);
        acc = fmaf(ov.z, uv.z, acc); acc = fmaf(ov.w, uv.w, acc);
    }
#pragma unroll
    for (int off = 32; off > 0; off >>= 1)
        acc += __shfl_xor(acc, off, 64);
    if (lane == 0)
        out[wid] = acc + b[r];
}

extern "C" void kernel_launch(void* const* d_in, const int* in_sizes, int n_in,
                              void* d_out, int out_size, void* d_ws, size_t ws_size,
                              hipStream_t stream)
{
    const float* emb     = (const float*)d_in[0];
    const float* W       = (const float*)d_in[1];
    const float* b       = (const float*)d_in[2];
    const int*   triples = (const int*)d_in[3];
    float*       out     = (float*)d_out;

    const int M = in_sizes[0] / NDIM;       // 100000 nodes
    const int T = in_sizes[3] / 3;          // 200000 triples

    const size_t pBytes  = (size_t)M * NCOL * sizeof(float);      // 51.2 MB
    const size_t bBytes  = (size_t)NDIM * NCOL * sizeof(short);   // 128 KB each
    const size_t need    = pBytes + 2 * bBytes;

    if (ws_size >= need) {
        float* P  = (float*)d_ws;
        short* Bh = (short*)((char*)d_ws + pBytes);
        short* Bl = Bh + (size_t)NDIM * NCOL;

        prep_B_kernel<<<(NDIM * NCOL) / 256, 256, 0, stream>>>(W, Bh, Bl);
        gemm_proj_kernel<<<(M + 127) / 128, 256, 0, stream>>>(emb, Bh, Bl, P, M);
        gather_score_kernel<<<(T + 255) / 256, 256, 0, stream>>>(P, b, triples, out, T);
    } else {
        const int block = 256;
        const int grid = (T + 3) / 4;       // 4 waves/block, 1 wave/triple
        kg_score_kernel<<<grid, block, 0, stream>>>(emb, W, b, triples, out, T);
    }
}

// Round 3
// 316.574 us; speedup vs baseline: 1.1219x; 1.1219x over previous
//
#include <hip/hip_runtime.h>
#include <hip/hip_bf16.h>

#define NDIM 512
#define NREL 64
#define NCOL 128          // 2 * NREL projection columns
#define KSTEPS (NDIM / 32)

typedef float f32x4 __attribute__((ext_vector_type(4)));
typedef short s16x8 __attribute__((ext_vector_type(8)));

typedef __attribute__((address_space(3))) void lds_void_t;
typedef const __attribute__((address_space(1))) void gvoid_t;

static __device__ __forceinline__ short f2bf_rne(float f) {
    union { float f; unsigned u; } v; v.f = f;
    unsigned u = v.u + 0x7fffu + ((v.u >> 16) & 1u);
    return (short)(u >> 16);
}
static __device__ __forceinline__ float bf2f(short h) {
    union { unsigned u; float f; } v;
    v.u = ((unsigned)(unsigned short)h) << 16;
    return v.f;
}

// ---------- Kernel A: W [64,1024] fp32 -> fragment-major bf16 hi/lo ----------
// B[k][n] = W[n&63][(n>>6)*512 + k];  frag (ks,c): lane l elem i ->
//   k = ks*32 + (l>>4)*8 + i, n = c*16 + (l&15); linear short idx = t.
// (verified correct in round 2 — unchanged)
__global__ __launch_bounds__(256) void prep_B_kernel(
    const float* __restrict__ W, short* __restrict__ Bh, short* __restrict__ Bl)
{
    const int t = blockIdx.x * 256 + threadIdx.x;     // [0, 65536)
    const int i  = t & 7;
    const int l  = (t >> 3) & 63;
    const int c  = (t >> 9) & 7;
    const int ks = t >> 12;
    const int k = ks * 32 + ((l >> 4) << 3) + i;
    const int n = (c << 4) + (l & 15);
    const float w = W[(n & 63) * (2 * NDIM) + (n >> 6) * NDIM + k];
    const short hi = f2bf_rne(w);
    const short lo = f2bf_rne(w - bf2f(hi));
    Bh[t] = hi;
    Bl[t] = lo;
}

// ---------- Kernel B: P[M,128] = emb[M,512] @ B[512,128] ----------
// 16 rows/wave (6250 waves), B double-buffered in LDS via global_load_lds,
// A software-pipelined one K-step ahead in registers.
__global__ __launch_bounds__(256, 4) void gemm_proj_kernel(
    const float* __restrict__ emb, const short* __restrict__ Bh,
    const short* __restrict__ Bl, float* __restrict__ P, int M)
{
    __shared__ __align__(16) short lds[2][2][4096];   // [buf][hi/lo][8KB]

    const int lane = threadIdx.x & 63;
    const int wave = threadIdx.x >> 6;
    const int rbase = (blockIdx.x * 4 + wave) * 16;
    const int rcol = lane & 15;
    const int koff = (lane >> 4) << 3;                // 0,8,16,24

    const float* abase = emb + (long)min(rbase + rcol, M - 1) * NDIM + koff;

    f32x4 acc[8];
#pragma unroll
    for (int c = 0; c < 8; ++c)
        acc[c] = (f32x4){0.f, 0.f, 0.f, 0.f};

    // stage K-step `ks` (16KB: bh 8KB + bl 8KB) into lds[b]; 4 chunks/wave
    auto stage = [&](int ks, int b) {
        const short* gbase = (wave < 2) ? Bh : Bl;
#pragma unroll
        for (int j = 0; j < 4; ++j) {
            const int chunk = wave * 4 + j;           // 0..15
            const short* srcp = gbase + (long)ks * 4096
                              + (long)(chunk & 7) * 512 + lane * 8;
            short* dstp = (short*)&lds[b][chunk >> 3][(chunk & 7) * 512];
            __builtin_amdgcn_global_load_lds((gvoid_t*)srcp, (lds_void_t*)dstp,
                                             16, 0, 0);
        }
    };

    // prologue: A regs for ks=0, stage B ks=0 into buf 0
    f32x4 aa = *(const f32x4*)(abase);
    f32x4 ab = *(const f32x4*)(abase + 4);
    stage(0, 0);
    __syncthreads();                                  // drains vmcnt too

#pragma unroll 1
    for (int ks = 0; ks < KSTEPS; ++ks) {
        const int buf = ks & 1;

        // issue next-tile staging + next-A prefetch first (latency overlap)
        if (ks + 1 < KSTEPS) stage(ks + 1, buf ^ 1);
        f32x4 na, nb;
        if (ks + 1 < KSTEPS) {
            na = *(const f32x4*)(abase + (ks + 1) * 32);
            nb = *(const f32x4*)(abase + (ks + 1) * 32 + 4);
        }

        // convert current A to bf16 hi/lo
        s16x8 ah, al;
#pragma unroll
        for (int j = 0; j < 4; ++j) {
            short h;
            h = f2bf_rne(aa[j]); ah[j]     = h; al[j]     = f2bf_rne(aa[j] - bf2f(h));
            h = f2bf_rne(ab[j]); ah[4 + j] = h; al[4 + j] = f2bf_rne(ab[j] - bf2f(h));
        }

        const s16x8* bh_p = (const s16x8*)(&lds[buf][0][0]) + lane;
        const s16x8* bl_p = (const s16x8*)(&lds[buf][1][0]) + lane;
#pragma unroll
        for (int c = 0; c < 8; ++c) {
            s16x8 bh = bh_p[c * 64];
            s16x8 bl = bl_p[c * 64];
            acc[c] = __builtin_amdgcn_mfma_f32_16x16x32_bf16(ah, bh, acc[c], 0, 0, 0);
            acc[c] = __builtin_amdgcn_mfma_f32_16x16x32_bf16(al, bh, acc[c], 0, 0, 0);
            acc[c] = __builtin_amdgcn_mfma_f32_16x16x32_bf16(ah, bl, acc[c], 0, 0, 0);
        }

        __syncthreads();      // waits vmcnt(0)+lgkmcnt(0): staged B + prefetched A done
        aa = na; ab = nb;
    }

    // C/D layout: col = lane&15, row = (lane>>4)*4 + reg
    const int rb = rbase + ((lane >> 4) << 2);
#pragma unroll
    for (int c = 0; c < 8; ++c) {
#pragma unroll
        for (int i = 0; i < 4; ++i) {
            const int r = rb + i;
            if (r < M)
                P[(long)r * NCOL + c * 16 + rcol] = acc[c][i];
        }
    }
}

// ---------- Kernel C: per-triple scalar gather from P ----------
__global__ __launch_bounds__(256) void gather_score_kernel(
    const float* __restrict__ P, const float* __restrict__ b,
    const int* __restrict__ triples, float* __restrict__ out, int T)
{
    const int t = blockIdx.x * 256 + threadIdx.x;
    if (t >= T) return;
    const int s = triples[t];
    const int r = triples[T + t];
    const int o = triples[2 * T + t];
    out[t] = P[(long)s * NCOL + r] + P[(long)o * NCOL + NREL + r] + b[r];
}

// ---------- Fallback: direct gather kernel (round-1, verified) ----------
__global__ __launch_bounds__(256) void kg_score_kernel(
    const float* __restrict__ emb, const float* __restrict__ W,
    const float* __restrict__ b, const int* __restrict__ triples,
    float* __restrict__ out, int T)
{
    const int wid  = (int)((blockIdx.x * (unsigned)blockDim.x + threadIdx.x) >> 6);
    const int lane = threadIdx.x & 63;
    if (wid >= T) return;

    const int s = triples[wid];
    const int r = triples[T + wid];
    const int o = triples[2 * T + wid];

    const float4* __restrict__ srow  = (const float4*)(emb + (long)s * NDIM);
    const float4* __restrict__ orow  = (const float4*)(emb + (long)o * NDIM);
    const float4* __restrict__ wsrow = (const float4*)(W + (long)r * (2 * NDIM));
    const float4* __restrict__ worow = wsrow + NDIM / 4;

    float acc = 0.0f;
#pragma unroll
    for (int k = 0; k < 2; ++k) {
        const int idx = lane + k * 64;
        float4 sv = srow[idx];
        float4 wv = wsrow[idx];
        acc = fmaf(sv.x, wv.x, acc); acc = fmaf(sv.y, wv.y, acc);
        acc = fmaf(sv.z, wv.z, acc); acc = fmaf(sv.w, wv.w, acc);
        float4 ov = orow[idx];
        float4 uv = worow[idx];
        acc = fmaf(ov.x, uv.x, acc); acc = fmaf(ov.y, uv.y, acc);
        acc = fmaf(ov.z, uv.z, acc); acc = fmaf(ov.w, uv.w, acc);
    }
#pragma unroll
    for (int off = 32; off > 0; off >>= 1)
        acc += __shfl_xor(acc, off, 64);
    if (lane == 0)
        out[wid] = acc + b[r];
}

extern "C" void kernel_launch(void* const* d_in, const int* in_sizes, int n_in,
                              void* d_out, int out_size, void* d_ws, size_t ws_size,
                              hipStream_t stream)
{
    const float* emb     = (const float*)d_in[0];
    const float* W       = (const float*)d_in[1];
    const float* b       = (const float*)d_in[2];
    const int*   triples = (const int*)d_in[3];
    float*       out     = (float*)d_out;

    const int M = in_sizes[0] / NDIM;       // 100000 nodes
    const int T = in_sizes[3] / 3;          // 200000 triples

    const size_t pBytes  = (size_t)M * NCOL * sizeof(float);      // 51.2 MB
    const size_t bBytes  = (size_t)NDIM * NCOL * sizeof(short);   // 128 KB each
    const size_t need    = pBytes + 2 * bBytes;

    if (ws_size >= need) {
        float* P  = (float*)d_ws;
        short* Bh = (short*)((char*)d_ws + pBytes);
        short* Bl = Bh + (size_t)NDIM * NCOL;

        prep_B_kernel<<<(NDIM * NCOL) / 256, 256, 0, stream>>>(W, Bh, Bl);
        gemm_proj_kernel<<<(M + 63) / 64, 256, 0, stream>>>(emb, Bh, Bl, P, M);
        gather_score_kernel<<<(T + 255) / 256, 256, 0, stream>>>(P, b, triples, out, T);
    } else {
        const int block = 256;
        const int grid = (T + 3) / 4;       // 4 waves/block, 1 wave/triple
        kg_score_kernel<<<grid, block, 0, stream>>>(emb, W, b, triples, out, T);
    }
}